// Round 7
// baseline (348.195 us; speedup 1.0000x reference)
//
#include <hip/hip_runtime.h>
#include <hip/hip_cooperative_groups.h>
#include <math.h>

namespace cg = cooperative_groups;

#define NATOM 20000
#define NNBR  64
#define KM    64
#define KM3   (KM*KM*KM)
#define NPAIR (NATOM*NNBR)

#define ALPHA_C 0.35f
#define KE_C    14.399645478425668f
#define TWO_OVER_SQRTPI 1.1283791670955126f
#define TWOPI_F 6.2831853071795864f
#define PI_F    3.14159265358979f
#define RC2     661.2244898f   /* (9/alpha)^2 */

// workspace layout (float offsets)
#define WS_RE    0
#define WS_IM    (KM3)
#define WS_MESH  (2*KM3)                  // zeroed ----
#define WS_GJ    (3*KM3)                  // 3*NATOM, zeroed
#define WS_PART  (3*KM3 + 3*NATOM)        // 64 slots * 16 fields, zeroed ----
#define WS_FI    (WS_PART + 1024)         // 3*NATOM, plain-stored
#define WS_POSQ  (WS_FI + 3*NATOM)        // 4*NATOM (float4, 16B-aligned)
#define WS_NBS   (WS_POSQ + 4*NATOM)      // NPAIR packed ints
#define ZERO_LEN (KM3 + 3*NATOM + 1024)
// part fields: 0=e_real, 1..6=geps_real, 7=sE_rec, 8..13=sV

__device__ __forceinline__ float M2f(float x){ return fmaxf(0.f, 1.f - fabsf(x - 1.f)); }
__device__ __forceinline__ float M3f(float x){ return (x*M2f(x) + (3.f-x)*M2f(x-1.f)) * 0.5f; }
__device__ __forceinline__ float M4f(float x){ return (x*M3f(x) + (4.f-x)*M3f(x-1.f)) * (1.f/3.f); }

__device__ __forceinline__ float wsum64(float v){
#pragma unroll
  for(int off=32; off>0; off>>=1) v += __shfl_xor(v, off, 64);
  return v;
}

// 3x3 inverse of row-major cell; returns |det|
__device__ __forceinline__ float hinv9(const float* __restrict__ cell, float* h){
  float m00=cell[0],m01=cell[1],m02=cell[2];
  float m10=cell[3],m11=cell[4],m12=cell[5];
  float m20=cell[6],m21=cell[7],m22=cell[8];
  float det = m00*(m11*m22-m12*m21) - m01*(m10*m22-m12*m20) + m02*(m10*m21-m11*m20);
  float id = 1.f/det;
  h[0]=(m11*m22-m12*m21)*id; h[1]=(m02*m21-m01*m22)*id; h[2]=(m01*m12-m02*m11)*id;
  h[3]=(m12*m20-m10*m22)*id; h[4]=(m00*m22-m02*m20)*id; h[5]=(m02*m10-m00*m12)*id;
  h[6]=(m10*m21-m11*m20)*id; h[7]=(m01*m20-m00*m21)*id; h[8]=(m00*m11-m01*m10)*id;
  return fabsf(det);
}

// fill forward twiddle tables (twr=cos, twi=-sin) from threads t<64
__device__ __forceinline__ void fill_tw(int t, float* twr, float* twi){
  if(t < 64){
    float ss, cc; sincosf((TWOPI_F/64.f)*(float)t, &ss, &cc);
    twr[t] = cc; twi[t] = -ss;
  }
}

// in-register 64-point FFT across the wave; sgn=+1 forward, -1 inverse
__device__ __forceinline__ void fft64t(float& xr, float& xi, int lane,
                                       const float* __restrict__ twr,
                                       const float* __restrict__ twi, float sgn){
#pragma unroll
  for(int k=0;k<6;k++){
    int half = 32 >> k;
    float or_ = __shfl_xor(xr, half, 64);
    float oi_ = __shfl_xor(xi, half, 64);
    bool hi = (lane & half) != 0;
    float sr = hi ? (or_ - xr) : (xr + or_);
    float si = hi ? (oi_ - xi) : (xi + oi_);
    int e = (lane & (half-1)) << k;
    float wr2 = hi ? twr[e] : 1.f;
    float wi2 = hi ? sgn*twi[e] : 0.f;
    xr = sr*wr2 - si*wi2;
    xi = sr*wi2 + si*wr2;
  }
  int rev = __brev((unsigned)lane) >> 26;
  xr = __shfl(xr, rev, 64);
  xi = __shfl(xi, rev, 64);
}

// ---------------- init: zero + pack posq + pack nbr/shifts ------------------
__global__ __launch_bounds__(256) void init_kernel(
    const float* __restrict__ pos, const float* __restrict__ q,
    const int* __restrict__ nbr, const int* __restrict__ shifts,
    float* __restrict__ zbase, float4* __restrict__ posq, int* __restrict__ nbs){
  int t = blockIdx.x*256 + threadIdx.x;
  if(t < ZERO_LEN) zbase[t] = 0.f;
  if(t < NATOM)
    posq[t] = make_float4(pos[3*t], pos[3*t+1], pos[3*t+2], q[t]);
  if(t < NPAIR){
    int j = nbr[t];
    int sx=shifts[3*t], sy=shifts[3*t+1], sz=shifts[3*t+2];
    int v;
    if(j < 0) v = -1;
    else v = (j & 0x7FFF) | ((sx+8)&15)<<15 | ((sy+8)&15)<<19 | ((sz+8)&15)<<23;
    nbs[t] = v;
  }
}

// ---------------- real-space pair sum: 4 atoms per wave ---------------------
__global__ __launch_bounds__(256) void real_kernel(
    const float4* __restrict__ posq, const int* __restrict__ nbs,
    const float* __restrict__ cell,
    float* __restrict__ fi, float* __restrict__ gj, float* __restrict__ part){
  int lane = threadIdx.x & 63;
  int wid  = blockIdx.x*4 + (threadIdx.x>>6);
  float c0=cell[0],c1=cell[1],c2=cell[2];
  float c3=cell[3],c4=cell[4],c5=cell[5];
  float c6=cell[6],c7=cell[7],c8=cell[8];
  float e=0.f, vxx=0.f,vyy=0.f,vzz=0.f,vxy=0.f,vxz=0.f,vyz=0.f;
#pragma unroll
  for(int it=0; it<4; ++it){
    int i = wid*4 + it;
    float4 pi4 = posq[i];
    int v = nbs[i*NNBR + lane];
    int j = v & 0x7FFF;
    int sx=((v>>15)&15)-8, sy=((v>>19)&15)-8, sz=((v>>23)&15)-8;
    bool self = (j==i) && (sx==0) && (sy==0) && (sz==0);
    float s=0.f, rx=0.f, ry=0.f, rz=0.f;
    if(v>=0 && !self){
      float4 pj = posq[j];
      rx = pj.x - pi4.x + sx*c0 + sy*c3 + sz*c6;
      ry = pj.y - pi4.y + sx*c1 + sy*c4 + sz*c7;
      rz = pj.z - pi4.z + sx*c2 + sy*c5 + sz*c8;
      float r2 = rx*rx + ry*ry + rz*rz;
      if(r2 > 0.f && r2 < RC2){
        float r = sqrtf(r2);
        float ar = ALPHA_C * r;
        float qq = pi4.w * pj.w;
        float ef = erfcf(ar);
        float ex = expf(-ar*ar);
        float ir = 1.f/r;
        e += 0.5f*qq*ef*ir;
        s  = 0.5f*qq*(ef + TWO_OVER_SQRTPI*ar*ex)*ir*ir*ir;
      }
    }
    float gx = s*rx, gy = s*ry, gz = s*rz;
    if(s != 0.f){
      unsafeAtomicAdd(&gj[3*j+0], -gx);
      unsafeAtomicAdd(&gj[3*j+1], -gy);
      unsafeAtomicAdd(&gj[3*j+2], -gz);
    }
    vxx -= s*rx*rx; vyy -= s*ry*ry; vzz -= s*rz*rz;
    vxy -= s*rx*ry; vxz -= s*rx*rz; vyz -= s*ry*rz;
    float tgx = wsum64(gx), tgy = wsum64(gy), tgz = wsum64(gz);
    if(lane==0){ fi[3*i]=tgx; fi[3*i+1]=tgy; fi[3*i+2]=tgz; }
  }
  e   = wsum64(e);
  vxx = wsum64(vxx); vyy = wsum64(vyy); vzz = wsum64(vzz);
  vxy = wsum64(vxy); vxz = wsum64(vxz); vyz = wsum64(vyz);
  if(lane==0){
    float* slot = part + (wid & 63)*16;
    unsafeAtomicAdd(&slot[0], e);
    unsafeAtomicAdd(&slot[1], vxx); unsafeAtomicAdd(&slot[2], vyy); unsafeAtomicAdd(&slot[3], vzz);
    unsafeAtomicAdd(&slot[4], vxy); unsafeAtomicAdd(&slot[5], vxz); unsafeAtomicAdd(&slot[6], vyz);
  }
}

// ---------------- B-spline spreading: one wave/atom, one lane/point ---------
__global__ __launch_bounds__(256) void spread_kernel(
    const float4* __restrict__ posq, const float* __restrict__ cell,
    float* __restrict__ mesh){
  int wid  = blockIdx.x*4 + (threadIdx.x>>6);
  int lane = threadIdx.x & 63;
  float h[9]; hinv9(cell, h);
  float4 pq = posq[wid];
  float u0=(pq.x*h[0]+pq.y*h[3]+pq.z*h[6])*(float)KM;
  float u1=(pq.x*h[1]+pq.y*h[4]+pq.z*h[7])*(float)KM;
  float u2=(pq.x*h[2]+pq.y*h[5]+pq.z*h[8])*(float)KM;
  float b0=floorf(u0), b1=floorf(u1), b2=floorf(u2);
  float t0=u0-b0, t1=u1-b1, t2=u2-b2;
  int i0=(int)b0, i1=(int)b1, i2=(int)b2;
  int a = lane>>4, b = (lane>>2)&3, c = lane&3;
  float w = pq.w * M4f(t0+(float)a) * M4f(t1+(float)b) * M4f(t2+(float)c);
  int ix=(i0-a+256)&63, iy=(i1-b+256)&63, iz=(i2-c+256)&63;
  unsafeAtomicAdd(&mesh[(ix*KM + iy)*KM + iz], w);
}

// ------------- fftAll: entire reciprocal conv in one cooperative kernel -----
// grid MUST be 256 blocks x 256 threads (co-resident on 256 CUs).
__global__ __launch_bounds__(256) void fftAll(
    float* __restrict__ re, float* __restrict__ im,
    const float* __restrict__ mesh, const float* __restrict__ cell,
    float* __restrict__ part){
  cg::grid_group grid = cg::this_grid();
  __shared__ float lr[64][17], li[64][17], twr[64], twi[64], cf[64];
  int t = threadIdx.x, lane = t&63, w = t>>6;
  int blk = blockIdx.x;
  fill_tw(t, twr, twi);
  if(t < 64){
    float p1 = TWOPI_F*(float)t/64.f;
    float s1,c1_,s2,c2_; sincosf(p1,&s1,&c1_); sincosf(2.f*p1,&s2,&c2_);
    float dre = (1.f/6.f) + (2.f/3.f)*c1_ + (1.f/6.f)*c2_;
    float dim = (2.f/3.f)*s1 + (1.f/6.f)*s2;
    cf[t] = 1.f/(dre*dre + dim*dim);
  }
  __syncthreads();

  // ---- phase 1: forward z (16 lines per block, coalesced) ----
#pragma unroll
  for(int k=0;k<4;k++){
    int idx = blk*1024 + k*256 + t;
    float xr = mesh[idx], xi = 0.f;
    fft64t(xr, xi, lane, twr, twi, 1.f);
    re[idx]=xr; im[idx]=xi;
  }
  grid.sync();

  // ---- phase 2: forward y (64y x 16z tile) ----
  {
    int x = blk>>2, z0 = (blk&3)*16;
    int off = x*4096 + z0;
#pragma unroll
    for(int k=0;k<4;k++){
      int e2 = k*256 + t; int y = e2>>4, zz = e2&15;
      lr[y][zz] = re[off + y*64 + zz];
      li[y][zz] = im[off + y*64 + zz];
    }
    __syncthreads();
#pragma unroll
    for(int qq=0; qq<4; qq++){
      int zz = w*4 + qq;
      float xr = lr[lane][zz], xi = li[lane][zz];
      fft64t(xr, xi, lane, twr, twi, 1.f);
      lr[lane][zz] = xr; li[lane][zz] = xi;
    }
    __syncthreads();
#pragma unroll
    for(int k=0;k<4;k++){
      int e2 = k*256 + t; int y = e2>>4, zz = e2&15;
      re[off + y*64 + zz] = lr[y][zz];
      im[off + y*64 + zz] = li[y][zz];
    }
  }
  grid.sync();

  // ---- phase 3: forward x + k-space multiply + energy/virial ----
  {
    int y = blk>>2, z0 = (blk&3)*16;
    float h[9]; hinv9(cell, h);
    float* rp = re + y*64 + z0;
    float* ip = im + y*64 + z0;
#pragma unroll
    for(int k=0;k<4;k++){
      int e2 = k*256 + t; int xI = e2>>4, zz = e2&15;
      lr[xI][zz] = rp[xI*4096 + zz];
      li[xI][zz] = ip[xI*4096 + zz];
    }
    __syncthreads();
    const float inv4a2 = 1.f/(4.f*ALPHA_C*ALPHA_C);
    float my_f = (float)((y<32)? y : y-64);
    float sE=0.f, v0=0.f,v1=0.f,v2=0.f,v3=0.f,v4=0.f,v5=0.f;
#pragma unroll
    for(int qq=0; qq<4; qq++){
      int zz = w*4 + qq; int z = z0 + zz;
      float xr = lr[lane][zz], xi = li[lane][zz];
      fft64t(xr, xi, lane, twr, twi, 1.f);   // lane = mx
      int mx = lane, mz = z;
      float fx = (float)((mx<32)? mx : mx-64);
      float fz = (float)((mz<32)? mz : mz-64);
      float kx = TWOPI_F*(fx*h[0] + my_f*h[1] + fz*h[2]);
      float ky = TWOPI_F*(fx*h[3] + my_f*h[4] + fz*h[5]);
      float kz = TWOPI_F*(fx*h[6] + my_f*h[7] + fz*h[8]);
      float k2 = kx*kx + ky*ky + kz*kz;
      float wk = 0.f;
      if(k2 > 0.f){
        float kern = expf(-k2*inv4a2)/k2;
        wk = kern * cf[mx]*cf[y]*cf[z];
        float q2 = xr*xr + xi*xi;
        sE += wk*q2;
        float fac = wk*q2*(inv4a2 + 1.f/k2)*2.f;
        v0 += fac*kx*kx; v1 += fac*ky*ky; v2 += fac*kz*kz;
        v3 += fac*kx*ky; v4 += fac*kx*kz; v5 += fac*ky*kz;
      }
      lr[lane][zz] = wk*xr; li[lane][zz] = wk*xi;
    }
    __syncthreads();
#pragma unroll
    for(int k=0;k<4;k++){
      int e2 = k*256 + t; int xI = e2>>4, zz = e2&15;
      rp[xI*4096 + zz] = lr[xI][zz];
      ip[xI*4096 + zz] = li[xI][zz];
    }
    sE = wsum64(sE);
    v0 = wsum64(v0); v1 = wsum64(v1); v2 = wsum64(v2);
    v3 = wsum64(v3); v4 = wsum64(v4); v5 = wsum64(v5);
    if(lane==0){
      float* slot = part + (((blk<<2)|w)&63)*16;
      unsafeAtomicAdd(&slot[7],  sE);
      unsafeAtomicAdd(&slot[8],  v0); unsafeAtomicAdd(&slot[9],  v1);
      unsafeAtomicAdd(&slot[10], v2); unsafeAtomicAdd(&slot[11], v3);
      unsafeAtomicAdd(&slot[12], v4); unsafeAtomicAdd(&slot[13], v5);
    }
  }
  grid.sync();

  // ---- phase 4: inverse x ----
  {
    int y = blk>>2, z0 = (blk&3)*16;
    float* rp = re + y*64 + z0;
    float* ip = im + y*64 + z0;
#pragma unroll
    for(int k=0;k<4;k++){
      int e2 = k*256 + t; int xI = e2>>4, zz = e2&15;
      lr[xI][zz] = rp[xI*4096 + zz];
      li[xI][zz] = ip[xI*4096 + zz];
    }
    __syncthreads();
#pragma unroll
    for(int qq=0; qq<4; qq++){
      int zz = w*4 + qq;
      float xr = lr[lane][zz], xi = li[lane][zz];
      fft64t(xr, xi, lane, twr, twi, -1.f);
      lr[lane][zz] = xr; li[lane][zz] = xi;
    }
    __syncthreads();
#pragma unroll
    for(int k=0;k<4;k++){
      int e2 = k*256 + t; int xI = e2>>4, zz = e2&15;
      rp[xI*4096 + zz] = lr[xI][zz];
      ip[xI*4096 + zz] = li[xI][zz];
    }
  }
  grid.sync();

  // ---- phase 5: inverse y ----
  {
    int x = blk>>2, z0 = (blk&3)*16;
    int off = x*4096 + z0;
#pragma unroll
    for(int k=0;k<4;k++){
      int e2 = k*256 + t; int y = e2>>4, zz = e2&15;
      lr[y][zz] = re[off + y*64 + zz];
      li[y][zz] = im[off + y*64 + zz];
    }
    __syncthreads();
#pragma unroll
    for(int qq=0; qq<4; qq++){
      int zz = w*4 + qq;
      float xr = lr[lane][zz], xi = li[lane][zz];
      fft64t(xr, xi, lane, twr, twi, -1.f);
      lr[lane][zz] = xr; li[lane][zz] = xi;
    }
    __syncthreads();
#pragma unroll
    for(int k=0;k<4;k++){
      int e2 = k*256 + t; int y = e2>>4, zz = e2&15;
      re[off + y*64 + zz] = lr[y][zz];
      im[off + y*64 + zz] = li[y][zz];
    }
  }
  grid.sync();

  // ---- phase 6: inverse z, write real part only (phi) ----
#pragma unroll
  for(int k=0;k<4;k++){
    int idx = blk*1024 + k*256 + t;
    float xr = re[idx], xi = im[idx];
    fft64t(xr, xi, lane, twr, twi, -1.f);
    re[idx]=xr;
  }
}

// ---------------- gather + merged finalize ----------------------------------
__global__ __launch_bounds__(256) void gather_kernel(
    const float4* __restrict__ posq, const float* __restrict__ cell,
    const float* __restrict__ phi,
    const float* __restrict__ fi, const float* __restrict__ gj,
    const float* __restrict__ part, float* __restrict__ out){
  __shared__ float sa[256], sb[256], facc[16];
  int wid  = blockIdx.x*4 + (threadIdx.x>>6);
  int lane = threadIdx.x & 63;
  float h[9]; float V = hinv9(cell, h);
  float4 pq = posq[wid];
  float u0=(pq.x*h[0]+pq.y*h[3]+pq.z*h[6])*(float)KM;
  float u1=(pq.x*h[1]+pq.y*h[4]+pq.z*h[7])*(float)KM;
  float u2=(pq.x*h[2]+pq.y*h[5]+pq.z*h[8])*(float)KM;
  float b0=floorf(u0), b1=floorf(u1), b2=floorf(u2);
  float t0=u0-b0, t1=u1-b1, t2=u2-b2;
  int i0=(int)b0, i1=(int)b1, i2=(int)b2;
  int a = lane>>4, b = (lane>>2)&3, c = lane&3;
  float fa=(float)a, fb=(float)b, fc=(float)c;
  float wxa=M4f(t0+fa), wyb=M4f(t1+fb), wzc=M4f(t2+fc);
  float dxa=M3f(t0+fa)-M3f(t0+fa-1.f);
  float dyb=M3f(t1+fb)-M3f(t1+fb-1.f);
  float dzc=M3f(t2+fc)-M3f(t2+fc-1.f);
  int ix=(i0-a+256)&63, iy=(i1-b+256)&63, iz=(i2-c+256)&63;
  float p = phi[(ix*KM + iy)*KM + iz];
  float Sx = wsum64(p*dxa*wyb*wzc);
  float Sy = wsum64(p*wxa*dyb*wzc);
  float Sz = wsum64(p*wxa*wyb*dzc);
  if(lane==0){
    float scale = pq.w * (2.f*TWOPI_F/V) * (float)KM;
    float g0 = scale*(Sx*h[0] + Sy*h[1] + Sz*h[2]);
    float g1 = scale*(Sx*h[3] + Sy*h[4] + Sz*h[5]);
    float g2 = scale*(Sx*h[6] + Sy*h[7] + Sz*h[8]);
    out[1+3*wid+0] = -KE_C*(fi[3*wid+0] + gj[3*wid+0] + g0);
    out[1+3*wid+1] = -KE_C*(fi[3*wid+1] + gj[3*wid+1] + g1);
    out[1+3*wid+2] = -KE_C*(fi[3*wid+2] + gj[3*wid+2] + g2);
  }
  if(blockIdx.x==0){
    int t = threadIdx.x;
    float qa=0.f, qb=0.f;
    for(int i=t;i<NATOM;i+=256){ float qv=posq[i].w; qa+=qv; qb+=qv*qv; }
    sa[t]=qa; sb[t]=qb; __syncthreads();
    for(int off=128; off>0; off>>=1){
      if(t<off){ sa[t]+=sa[t+off]; sb[t]+=sb[t+off]; } __syncthreads();
    }
    if(t<14){ float s=0.f; for(int sl=0;sl<64;sl++) s+=part[sl*16+t]; facc[t]=s; }
    __syncthreads();
    if(t==0){
      float qtot = sa[0], sumq2 = sb[0];
      float a2 = ALPHA_C*ALPHA_C;
      float pref = TWOPI_F/V;
      float e_real = facc[0];
      float e_rec  = pref*facc[7];
      float e_self = -(ALPHA_C/sqrtf(PI_F))*sumq2;
      float e_bg   = -(PI_F/(2.f*a2*V))*qtot*qtot;
      out[0] = (e_real + e_rec + e_self + e_bg)*KE_C;
      float gxx = facc[1] + pref*facc[8]  - e_rec - e_bg;
      float gyy = facc[2] + pref*facc[9]  - e_rec - e_bg;
      float gzz = facc[3] + pref*facc[10] - e_rec - e_bg;
      float gxy = facc[4] + pref*facc[11];
      float gxz = facc[5] + pref*facc[12];
      float gyz = facc[6] + pref*facc[13];
      float cc = -KE_C/V;
      float* st = out + 1 + 3*NATOM;
      st[0]=cc*gxx; st[4]=cc*gyy; st[8]=cc*gzz;
      st[1]=cc*gxy; st[3]=cc*gxy;
      st[2]=cc*gxz; st[6]=cc*gxz;
      st[5]=cc*gyz; st[7]=cc*gyz;
    }
  }
}

extern "C" void kernel_launch(void* const* d_in, const int* in_sizes, int n_in,
                              void* d_out, int out_size, void* d_ws, size_t ws_size,
                              hipStream_t stream) {
  const float* pos  = (const float*)d_in[0];
  const float* q    = (const float*)d_in[1];
  const float* cell = (const float*)d_in[2];
  const int* nbr    = (const int*)d_in[3];
  const int* shifts = (const int*)d_in[4];
  float* out = (float*)d_out;
  float* ws  = (float*)d_ws;
  float*  bufRe = ws + WS_RE;
  float*  bufIm = ws + WS_IM;
  float*  mesh  = ws + WS_MESH;
  float*  gj    = ws + WS_GJ;
  float*  part  = ws + WS_PART;
  float*  fi    = ws + WS_FI;
  float4* posq  = (float4*)(ws + WS_POSQ);
  int*    nbs   = (int*)(ws + WS_NBS);

  init_kernel<<<(NPAIR+255)/256,256,0,stream>>>(pos, q, nbr, shifts, mesh, posq, nbs);
  real_kernel<<<1250,256,0,stream>>>(posq, nbs, cell, fi, gj, part);
  spread_kernel<<<5000,256,0,stream>>>(posq, cell, mesh);
  {
    const float* meshc = mesh;
    void* args[] = { (void*)&bufRe, (void*)&bufIm, (void*)&meshc, (void*)&cell, (void*)&part };
    hipLaunchCooperativeKernel((void*)fftAll, dim3(256), dim3(256), args, 0, stream);
  }
  gather_kernel<<<5000,256,0,stream>>>(posq, cell, bufRe, fi, gj, part, out);
}

// Round 8
// 189.136 us; speedup vs baseline: 1.8410x; 1.8410x over previous
//
#include <hip/hip_runtime.h>
#include <math.h>

#define NATOM 20000
#define NNBR  64
#define KM    64
#define KM3   (KM*KM*KM)
#define NPAIR (NATOM*NNBR)

#define ALPHA_C 0.35f
#define KE_C    14.399645478425668f
#define TWO_OVER_SQRTPI 1.1283791670955126f
#define TWOPI_F 6.2831853071795864f
#define PI_F    3.14159265358979f
#define RC2     661.2244898f   /* (9/alpha)^2 */

// workspace layout (float offsets)
#define WS_RE    0
#define WS_IM    (KM3)
#define WS_MESH  (2*KM3)                  // zeroed ----
#define WS_GJ    (3*KM3)                  // 3*NATOM, zeroed
#define WS_PART  (3*KM3 + 3*NATOM)        // 64 slots * 16 fields, zeroed ----
#define WS_FI    (WS_PART + 1024)         // 3*NATOM, plain-stored
#define WS_POSQ  (WS_FI + 3*NATOM)        // 4*NATOM (float4, 16B-aligned)
#define WS_NBS   (WS_POSQ + 4*NATOM)      // NPAIR packed ints
#define ZERO_LEN (KM3 + 3*NATOM + 1024)
// part fields: 0=e_real, 1..6=geps_real, 7=sE_rec, 8..13=sV

__device__ __forceinline__ float M2f(float x){ return fmaxf(0.f, 1.f - fabsf(x - 1.f)); }
__device__ __forceinline__ float M3f(float x){ return (x*M2f(x) + (3.f-x)*M2f(x-1.f)) * 0.5f; }
__device__ __forceinline__ float M4f(float x){ return (x*M3f(x) + (4.f-x)*M3f(x-1.f)) * (1.f/3.f); }

__device__ __forceinline__ float wsum64(float v){
#pragma unroll
  for(int off=32; off>0; off>>=1) v += __shfl_xor(v, off, 64);
  return v;
}

// 3x3 inverse of row-major cell; returns |det|
__device__ __forceinline__ float hinv9(const float* __restrict__ cell, float* h){
  float m00=cell[0],m01=cell[1],m02=cell[2];
  float m10=cell[3],m11=cell[4],m12=cell[5];
  float m20=cell[6],m21=cell[7],m22=cell[8];
  float det = m00*(m11*m22-m12*m21) - m01*(m10*m22-m12*m20) + m02*(m10*m21-m11*m20);
  float id = 1.f/det;
  h[0]=(m11*m22-m12*m21)*id; h[1]=(m02*m21-m01*m22)*id; h[2]=(m01*m12-m02*m11)*id;
  h[3]=(m12*m20-m10*m22)*id; h[4]=(m00*m22-m02*m20)*id; h[5]=(m02*m10-m00*m12)*id;
  h[6]=(m10*m21-m11*m20)*id; h[7]=(m01*m20-m00*m21)*id; h[8]=(m00*m11-m01*m10)*id;
  return fabsf(det);
}

// fill forward twiddle tables (twr=cos, twi=-sin) from threads t<64
__device__ __forceinline__ void fill_tw(int t, float* twr, float* twi){
  if(t < 64){
    float ss, cc; sincosf((TWOPI_F/64.f)*(float)t, &ss, &cc);
    twr[t] = cc; twi[t] = -ss;
  }
}

// in-register 64-point FFT across the wave; sgn=+1 forward, -1 inverse
__device__ __forceinline__ void fft64t(float& xr, float& xi, int lane,
                                       const float* __restrict__ twr,
                                       const float* __restrict__ twi, float sgn){
#pragma unroll
  for(int k=0;k<6;k++){
    int half = 32 >> k;
    float or_ = __shfl_xor(xr, half, 64);
    float oi_ = __shfl_xor(xi, half, 64);
    bool hi = (lane & half) != 0;
    float sr = hi ? (or_ - xr) : (xr + or_);
    float si = hi ? (oi_ - xi) : (xi + oi_);
    int e = (lane & (half-1)) << k;
    float wr2 = hi ? twr[e] : 1.f;
    float wi2 = hi ? sgn*twi[e] : 0.f;
    xr = sr*wr2 - si*wi2;
    xi = sr*wi2 + si*wr2;
  }
  int rev = __brev((unsigned)lane) >> 26;
  xr = __shfl(xr, rev, 64);
  xi = __shfl(xi, rev, 64);
}

// ---------------- init: zero + pack posq + pack nbr/shifts ------------------
__global__ __launch_bounds__(256) void init_kernel(
    const float* __restrict__ pos, const float* __restrict__ q,
    const int* __restrict__ nbr, const int* __restrict__ shifts,
    float* __restrict__ zbase, float4* __restrict__ posq, int* __restrict__ nbs){
  int t = blockIdx.x*256 + threadIdx.x;
  if(t < ZERO_LEN) zbase[t] = 0.f;
  if(t < NATOM)
    posq[t] = make_float4(pos[3*t], pos[3*t+1], pos[3*t+2], q[t]);
  if(t < NPAIR){
    int j = nbr[t];
    int sx=shifts[3*t], sy=shifts[3*t+1], sz=shifts[3*t+2];
    int v;
    if(j < 0) v = -1;
    else v = (j & 0x7FFF) | ((sx+8)&15)<<15 | ((sy+8)&15)<<19 | ((sz+8)&15)<<23;
    nbs[t] = v;
  }
}

// ---------------- real-space pair sum: 4 atoms per wave ---------------------
__global__ __launch_bounds__(256) void real_kernel(
    const float4* __restrict__ posq, const int* __restrict__ nbs,
    const float* __restrict__ cell,
    float* __restrict__ fi, float* __restrict__ gj, float* __restrict__ part){
  int lane = threadIdx.x & 63;
  int wid  = blockIdx.x*4 + (threadIdx.x>>6);
  float c0=cell[0],c1=cell[1],c2=cell[2];
  float c3=cell[3],c4=cell[4],c5=cell[5];
  float c6=cell[6],c7=cell[7],c8=cell[8];
  float e=0.f, vxx=0.f,vyy=0.f,vzz=0.f,vxy=0.f,vxz=0.f,vyz=0.f;
#pragma unroll
  for(int it=0; it<4; ++it){
    int i = wid*4 + it;
    float4 pi4 = posq[i];
    int v = nbs[i*NNBR + lane];
    int j = v & 0x7FFF;
    int sx=((v>>15)&15)-8, sy=((v>>19)&15)-8, sz=((v>>23)&15)-8;
    bool self = (j==i) && (sx==0) && (sy==0) && (sz==0);
    float s=0.f, rx=0.f, ry=0.f, rz=0.f;
    if(v>=0 && !self){
      float4 pj = posq[j];
      rx = pj.x - pi4.x + sx*c0 + sy*c3 + sz*c6;
      ry = pj.y - pi4.y + sx*c1 + sy*c4 + sz*c7;
      rz = pj.z - pi4.z + sx*c2 + sy*c5 + sz*c8;
      float r2 = rx*rx + ry*ry + rz*rz;
      if(r2 > 0.f && r2 < RC2){
        float r = sqrtf(r2);
        float ar = ALPHA_C * r;
        float qq = pi4.w * pj.w;
        float ef = erfcf(ar);
        float ex = expf(-ar*ar);
        float ir = 1.f/r;
        e += 0.5f*qq*ef*ir;
        s  = 0.5f*qq*(ef + TWO_OVER_SQRTPI*ar*ex)*ir*ir*ir;
      }
    }
    float gx = s*rx, gy = s*ry, gz = s*rz;
    if(s != 0.f){
      unsafeAtomicAdd(&gj[3*j+0], -gx);
      unsafeAtomicAdd(&gj[3*j+1], -gy);
      unsafeAtomicAdd(&gj[3*j+2], -gz);
    }
    vxx -= s*rx*rx; vyy -= s*ry*ry; vzz -= s*rz*rz;
    vxy -= s*rx*ry; vxz -= s*rx*rz; vyz -= s*ry*rz;
    float tgx = wsum64(gx), tgy = wsum64(gy), tgz = wsum64(gz);
    if(lane==0){ fi[3*i]=tgx; fi[3*i+1]=tgy; fi[3*i+2]=tgz; }
  }
  e   = wsum64(e);
  vxx = wsum64(vxx); vyy = wsum64(vyy); vzz = wsum64(vzz);
  vxy = wsum64(vxy); vxz = wsum64(vxz); vyz = wsum64(vyz);
  if(lane==0){
    float* slot = part + (wid & 63)*16;
    unsafeAtomicAdd(&slot[0], e);
    unsafeAtomicAdd(&slot[1], vxx); unsafeAtomicAdd(&slot[2], vyy); unsafeAtomicAdd(&slot[3], vzz);
    unsafeAtomicAdd(&slot[4], vxy); unsafeAtomicAdd(&slot[5], vxz); unsafeAtomicAdd(&slot[6], vyz);
  }
}

// ---------------- B-spline spreading: one wave/atom, one lane/point ---------
__global__ __launch_bounds__(256) void spread_kernel(
    const float4* __restrict__ posq, const float* __restrict__ cell,
    float* __restrict__ mesh){
  int wid  = blockIdx.x*4 + (threadIdx.x>>6);
  int lane = threadIdx.x & 63;
  float h[9]; hinv9(cell, h);
  float4 pq = posq[wid];
  float u0=(pq.x*h[0]+pq.y*h[3]+pq.z*h[6])*(float)KM;
  float u1=(pq.x*h[1]+pq.y*h[4]+pq.z*h[7])*(float)KM;
  float u2=(pq.x*h[2]+pq.y*h[5]+pq.z*h[8])*(float)KM;
  float b0=floorf(u0), b1=floorf(u1), b2=floorf(u2);
  float t0=u0-b0, t1=u1-b1, t2=u2-b2;
  int i0=(int)b0, i1=(int)b1, i2=(int)b2;
  int a = lane>>4, b = (lane>>2)&3, c = lane&3;
  float w = pq.w * M4f(t0+(float)a) * M4f(t1+(float)b) * M4f(t2+(float)c);
  int ix=(i0-a+256)&63, iy=(i1-b+256)&63, iz=(i2-c+256)&63;
  unsafeAtomicAdd(&mesh[(ix*KM + iy)*KM + iz], w);
}

// ---------------- fftZ forward: 4 contiguous z-lines per block --------------
__global__ __launch_bounds__(256) void fftZF(const float* __restrict__ mesh,
                                             float* __restrict__ re, float* __restrict__ im){
  __shared__ float twr[64], twi[64];
  int t = threadIdx.x, lane = t&63;
  fill_tw(t, twr, twi);
  __syncthreads();
  int idx = blockIdx.x*256 + t;
  float xr = mesh[idx], xi = 0.f;
  fft64t(xr, xi, lane, twr, twi, 1.f);
  re[idx]=xr; im[idx]=xi;
}

// ---------------- fftZ inverse: write real part only (phi) ------------------
__global__ __launch_bounds__(256) void fftZI(float* __restrict__ re, const float* __restrict__ im){
  __shared__ float twr[64], twi[64];
  int t = threadIdx.x, lane = t&63;
  fill_tw(t, twr, twi);
  __syncthreads();
  int idx = blockIdx.x*256 + t;
  float xr = re[idx], xi = im[idx];
  fft64t(xr, xi, lane, twr, twi, -1.f);
  re[idx]=xr;
}

// ---------------- fftY: 64y x 16z tile per block, dir = +-1 -----------------
__global__ __launch_bounds__(256) void fftY(float* __restrict__ re, float* __restrict__ im,
                                            float sgn){
  __shared__ float lr[64][17], li[64][17], twr[64], twi[64];
  int t = threadIdx.x, lane = t&63, w = t>>6;
  fill_tw(t, twr, twi);
  int x = blockIdx.x>>2, z0 = (blockIdx.x&3)*16;
  int off = x*4096 + z0;
#pragma unroll
  for(int k=0;k<4;k++){
    int e = k*256 + t; int y = e>>4, zz = e&15;
    lr[y][zz] = re[off + y*64 + zz];
    li[y][zz] = im[off + y*64 + zz];
  }
  __syncthreads();
#pragma unroll
  for(int qq=0; qq<4; qq++){
    int zz = w*4 + qq;
    float xr = lr[lane][zz], xi = li[lane][zz];
    fft64t(xr, xi, lane, twr, twi, sgn);
    lr[lane][zz] = xr; li[lane][zz] = xi;
  }
  __syncthreads();
#pragma unroll
  for(int k=0;k<4;k++){
    int e = k*256 + t; int y = e>>4, zz = e&15;
    re[off + y*64 + zz] = lr[y][zz];
    im[off + y*64 + zz] = li[y][zz];
  }
}

// ---------------- fftB: forward x + k-space multiply + energy/virial --------
__global__ __launch_bounds__(256) void fftB(float* __restrict__ re, float* __restrict__ im,
                                            const float* __restrict__ cell,
                                            float* __restrict__ part){
  __shared__ float lr[64][17], li[64][17], cf[64], twr[64], twi[64];
  int t = threadIdx.x, lane = t&63, w = t>>6;
  int y = blockIdx.x>>2, z0 = (blockIdx.x&3)*16;
  float h[9]; hinv9(cell, h);
  fill_tw(t, twr, twi);
  if(t < 64){
    float p1 = TWOPI_F*(float)t/64.f;
    float s1,c1_,s2,c2_; sincosf(p1,&s1,&c1_); sincosf(2.f*p1,&s2,&c2_);
    float dre = (1.f/6.f) + (2.f/3.f)*c1_ + (1.f/6.f)*c2_;
    float dim = (2.f/3.f)*s1 + (1.f/6.f)*s2;
    cf[t] = 1.f/(dre*dre + dim*dim);
  }
  float* rp = re + y*64 + z0;
  float* ip = im + y*64 + z0;
#pragma unroll
  for(int k=0;k<4;k++){
    int e = k*256 + t; int xI = e>>4, zz = e&15;
    lr[xI][zz] = rp[xI*4096 + zz];
    li[xI][zz] = ip[xI*4096 + zz];
  }
  __syncthreads();
  const float inv4a2 = 1.f/(4.f*ALPHA_C*ALPHA_C);
  float my_f = (float)((y<32)? y : y-64);
  float sE=0.f, v0=0.f,v1=0.f,v2=0.f,v3=0.f,v4=0.f,v5=0.f;
#pragma unroll
  for(int qq=0; qq<4; qq++){
    int zz = w*4 + qq; int z = z0 + zz;
    float xr = lr[lane][zz], xi = li[lane][zz];
    fft64t(xr, xi, lane, twr, twi, 1.f);   // lane = mx
    int mx = lane, mz = z;
    float fx = (float)((mx<32)? mx : mx-64);
    float fz = (float)((mz<32)? mz : mz-64);
    float kx = TWOPI_F*(fx*h[0] + my_f*h[1] + fz*h[2]);
    float ky = TWOPI_F*(fx*h[3] + my_f*h[4] + fz*h[5]);
    float kz = TWOPI_F*(fx*h[6] + my_f*h[7] + fz*h[8]);
    float k2 = kx*kx + ky*ky + kz*kz;
    float wk = 0.f;
    if(k2 > 0.f){
      float kern = expf(-k2*inv4a2)/k2;
      wk = kern * cf[mx]*cf[y]*cf[z];
      float q2 = xr*xr + xi*xi;
      sE += wk*q2;
      float fac = wk*q2*(inv4a2 + 1.f/k2)*2.f;
      v0 += fac*kx*kx; v1 += fac*ky*ky; v2 += fac*kz*kz;
      v3 += fac*kx*ky; v4 += fac*kx*kz; v5 += fac*ky*kz;
    }
    lr[lane][zz] = wk*xr; li[lane][zz] = wk*xi;
  }
  __syncthreads();
#pragma unroll
  for(int k=0;k<4;k++){
    int e = k*256 + t; int xI = e>>4, zz = e&15;
    rp[xI*4096 + zz] = lr[xI][zz];
    ip[xI*4096 + zz] = li[xI][zz];
  }
  sE = wsum64(sE);
  v0 = wsum64(v0); v1 = wsum64(v1); v2 = wsum64(v2);
  v3 = wsum64(v3); v4 = wsum64(v4); v5 = wsum64(v5);
  if(lane==0){
    float* slot = part + (((blockIdx.x<<2)|w)&63)*16;
    unsafeAtomicAdd(&slot[7],  sE);
    unsafeAtomicAdd(&slot[8],  v0); unsafeAtomicAdd(&slot[9],  v1);
    unsafeAtomicAdd(&slot[10], v2); unsafeAtomicAdd(&slot[11], v3);
    unsafeAtomicAdd(&slot[12], v4); unsafeAtomicAdd(&slot[13], v5);
  }
}

// ---------------- fftC: inverse x ------------------------------------------
__global__ __launch_bounds__(256) void fftC(float* __restrict__ re, float* __restrict__ im){
  __shared__ float lr[64][17], li[64][17], twr[64], twi[64];
  int t = threadIdx.x, lane = t&63, w = t>>6;
  fill_tw(t, twr, twi);
  int y = blockIdx.x>>2, z0 = (blockIdx.x&3)*16;
  float* rp = re + y*64 + z0;
  float* ip = im + y*64 + z0;
#pragma unroll
  for(int k=0;k<4;k++){
    int e = k*256 + t; int xI = e>>4, zz = e&15;
    lr[xI][zz] = rp[xI*4096 + zz];
    li[xI][zz] = ip[xI*4096 + zz];
  }
  __syncthreads();
#pragma unroll
  for(int qq=0; qq<4; qq++){
    int zz = w*4 + qq;
    float xr = lr[lane][zz], xi = li[lane][zz];
    fft64t(xr, xi, lane, twr, twi, -1.f);
    lr[lane][zz] = xr; li[lane][zz] = xi;
  }
  __syncthreads();
#pragma unroll
  for(int k=0;k<4;k++){
    int e = k*256 + t; int xI = e>>4, zz = e&15;
    rp[xI*4096 + zz] = lr[xI][zz];
    ip[xI*4096 + zz] = li[xI][zz];
  }
}

// ---------------- gather + merged finalize ----------------------------------
__global__ __launch_bounds__(256) void gather_kernel(
    const float4* __restrict__ posq, const float* __restrict__ cell,
    const float* __restrict__ phi,
    const float* __restrict__ fi, const float* __restrict__ gj,
    const float* __restrict__ part, float* __restrict__ out){
  __shared__ float sa[256], sb[256], facc[16];
  int wid  = blockIdx.x*4 + (threadIdx.x>>6);
  int lane = threadIdx.x & 63;
  float h[9]; float V = hinv9(cell, h);
  float4 pq = posq[wid];
  float u0=(pq.x*h[0]+pq.y*h[3]+pq.z*h[6])*(float)KM;
  float u1=(pq.x*h[1]+pq.y*h[4]+pq.z*h[7])*(float)KM;
  float u2=(pq.x*h[2]+pq.y*h[5]+pq.z*h[8])*(float)KM;
  float b0=floorf(u0), b1=floorf(u1), b2=floorf(u2);
  float t0=u0-b0, t1=u1-b1, t2=u2-b2;
  int i0=(int)b0, i1=(int)b1, i2=(int)b2;
  int a = lane>>4, b = (lane>>2)&3, c = lane&3;
  float fa=(float)a, fb=(float)b, fc=(float)c;
  float wxa=M4f(t0+fa), wyb=M4f(t1+fb), wzc=M4f(t2+fc);
  float dxa=M3f(t0+fa)-M3f(t0+fa-1.f);
  float dyb=M3f(t1+fb)-M3f(t1+fb-1.f);
  float dzc=M3f(t2+fc)-M3f(t2+fc-1.f);
  int ix=(i0-a+256)&63, iy=(i1-b+256)&63, iz=(i2-c+256)&63;
  float p = phi[(ix*KM + iy)*KM + iz];
  float Sx = wsum64(p*dxa*wyb*wzc);
  float Sy = wsum64(p*wxa*dyb*wzc);
  float Sz = wsum64(p*wxa*wyb*dzc);
  if(lane==0){
    float scale = pq.w * (2.f*TWOPI_F/V) * (float)KM;
    float g0 = scale*(Sx*h[0] + Sy*h[1] + Sz*h[2]);
    float g1 = scale*(Sx*h[3] + Sy*h[4] + Sz*h[5]);
    float g2 = scale*(Sx*h[6] + Sy*h[7] + Sz*h[8]);
    out[1+3*wid+0] = -KE_C*(fi[3*wid+0] + gj[3*wid+0] + g0);
    out[1+3*wid+1] = -KE_C*(fi[3*wid+1] + gj[3*wid+1] + g1);
    out[1+3*wid+2] = -KE_C*(fi[3*wid+2] + gj[3*wid+2] + g2);
  }
  if(blockIdx.x==0){
    int t = threadIdx.x;
    float qa=0.f, qb=0.f;
    for(int i=t;i<NATOM;i+=256){ float qv=posq[i].w; qa+=qv; qb+=qv*qv; }
    sa[t]=qa; sb[t]=qb; __syncthreads();
    for(int off=128; off>0; off>>=1){
      if(t<off){ sa[t]+=sa[t+off]; sb[t]+=sb[t+off]; } __syncthreads();
    }
    if(t<14){ float s=0.f; for(int sl=0;sl<64;sl++) s+=part[sl*16+t]; facc[t]=s; }
    __syncthreads();
    if(t==0){
      float qtot = sa[0], sumq2 = sb[0];
      float a2 = ALPHA_C*ALPHA_C;
      float pref = TWOPI_F/V;
      float e_real = facc[0];
      float e_rec  = pref*facc[7];
      float e_self = -(ALPHA_C/sqrtf(PI_F))*sumq2;
      float e_bg   = -(PI_F/(2.f*a2*V))*qtot*qtot;
      out[0] = (e_real + e_rec + e_self + e_bg)*KE_C;
      float gxx = facc[1] + pref*facc[8]  - e_rec - e_bg;
      float gyy = facc[2] + pref*facc[9]  - e_rec - e_bg;
      float gzz = facc[3] + pref*facc[10] - e_rec - e_bg;
      float gxy = facc[4] + pref*facc[11];
      float gxz = facc[5] + pref*facc[12];
      float gyz = facc[6] + pref*facc[13];
      float cc = -KE_C/V;
      float* st = out + 1 + 3*NATOM;
      st[0]=cc*gxx; st[4]=cc*gyy; st[8]=cc*gzz;
      st[1]=cc*gxy; st[3]=cc*gxy;
      st[2]=cc*gxz; st[6]=cc*gxz;
      st[5]=cc*gyz; st[7]=cc*gyz;
    }
  }
}

extern "C" void kernel_launch(void* const* d_in, const int* in_sizes, int n_in,
                              void* d_out, int out_size, void* d_ws, size_t ws_size,
                              hipStream_t stream) {
  const float* pos  = (const float*)d_in[0];
  const float* q    = (const float*)d_in[1];
  const float* cell = (const float*)d_in[2];
  const int* nbr    = (const int*)d_in[3];
  const int* shifts = (const int*)d_in[4];
  float* out = (float*)d_out;
  float* ws  = (float*)d_ws;
  float*  bufRe = ws + WS_RE;
  float*  bufIm = ws + WS_IM;
  float*  mesh  = ws + WS_MESH;
  float*  gj    = ws + WS_GJ;
  float*  part  = ws + WS_PART;
  float*  fi    = ws + WS_FI;
  float4* posq  = (float4*)(ws + WS_POSQ);
  int*    nbs   = (int*)(ws + WS_NBS);

  init_kernel<<<(NPAIR+255)/256,256,0,stream>>>(pos, q, nbr, shifts, mesh, posq, nbs);
  real_kernel<<<1250,256,0,stream>>>(posq, nbs, cell, fi, gj, part);
  spread_kernel<<<5000,256,0,stream>>>(posq, cell, mesh);
  fftZF<<<1024,256,0,stream>>>(mesh, bufRe, bufIm);
  fftY <<< 256,256,0,stream>>>(bufRe, bufIm, 1.f);
  fftB <<< 256,256,0,stream>>>(bufRe, bufIm, cell, part);
  fftC <<< 256,256,0,stream>>>(bufRe, bufIm);
  fftY <<< 256,256,0,stream>>>(bufRe, bufIm, -1.f);
  fftZI<<<1024,256,0,stream>>>(bufRe, bufIm);
  gather_kernel<<<5000,256,0,stream>>>(posq, cell, bufRe, fi, gj, part, out);
}

// Round 9
// 185.552 us; speedup vs baseline: 1.8765x; 1.0193x over previous
//
#include <hip/hip_runtime.h>
#include <math.h>

#define NATOM 20000
#define NNBR  64
#define KM    64
#define KM3   (KM*KM*KM)
#define NPAIR (NATOM*NNBR)

#define ALPHA_C 0.35f
#define KE_C    14.399645478425668f
#define TWO_OVER_SQRTPI 1.1283791670955126f
#define TWOPI_F 6.2831853071795864f
#define PI_F    3.14159265358979f
#define RC2     661.2244898f   /* (9/alpha)^2 */

// workspace layout (float offsets)
#define WS_RE    0
#define WS_IM    (KM3)
#define WS_MESH  (2*KM3)                  // zeroed ----
#define WS_GJ    (3*KM3)                  // 3*NATOM, zeroed
#define WS_PART  (3*KM3 + 3*NATOM)        // 64 slots * 16 fields, zeroed ----
#define WS_FI    (WS_PART + 1024)         // 3*NATOM, plain-stored
#define WS_POSQ  (WS_FI + 3*NATOM)        // 4*NATOM (float4, 16B-aligned)
#define WS_NBS   (WS_POSQ + 4*NATOM)      // NPAIR packed ints
#define ZERO_LEN (KM3 + 3*NATOM + 1024)
// part fields: 0=e_real, 1..6=geps_real, 7=sE_rec, 8..13=sV

__device__ __forceinline__ float M2f(float x){ return fmaxf(0.f, 1.f - fabsf(x - 1.f)); }
__device__ __forceinline__ float M3f(float x){ return (x*M2f(x) + (3.f-x)*M2f(x-1.f)) * 0.5f; }
__device__ __forceinline__ float M4f(float x){ return (x*M3f(x) + (4.f-x)*M3f(x-1.f)) * (1.f/3.f); }

__device__ __forceinline__ float wsum64(float v){
#pragma unroll
  for(int off=32; off>0; off>>=1) v += __shfl_xor(v, off, 64);
  return v;
}

// 3x3 inverse of row-major cell; returns |det|
__device__ __forceinline__ float hinv9(const float* __restrict__ cell, float* h){
  float m00=cell[0],m01=cell[1],m02=cell[2];
  float m10=cell[3],m11=cell[4],m12=cell[5];
  float m20=cell[6],m21=cell[7],m22=cell[8];
  float det = m00*(m11*m22-m12*m21) - m01*(m10*m22-m12*m20) + m02*(m10*m21-m11*m20);
  float id = 1.f/det;
  h[0]=(m11*m22-m12*m21)*id; h[1]=(m02*m21-m01*m22)*id; h[2]=(m01*m12-m02*m11)*id;
  h[3]=(m12*m20-m10*m22)*id; h[4]=(m00*m22-m02*m20)*id; h[5]=(m02*m10-m00*m12)*id;
  h[6]=(m10*m21-m11*m20)*id; h[7]=(m01*m20-m00*m21)*id; h[8]=(m00*m11-m01*m10)*id;
  return fabsf(det);
}

// fill forward twiddle tables (twr=cos, twi=-sin) from threads t<64
__device__ __forceinline__ void fill_tw(int t, float* twr, float* twi){
  if(t < 64){
    float ss, cc; sincosf((TWOPI_F/64.f)*(float)t, &ss, &cc);
    twr[t] = cc; twi[t] = -ss;
  }
}

// in-register 64-point FFT across the wave; sgn=+1 forward, -1 inverse
__device__ __forceinline__ void fft64t(float& xr, float& xi, int lane,
                                       const float* __restrict__ twr,
                                       const float* __restrict__ twi, float sgn){
#pragma unroll
  for(int k=0;k<6;k++){
    int half = 32 >> k;
    float or_ = __shfl_xor(xr, half, 64);
    float oi_ = __shfl_xor(xi, half, 64);
    bool hi = (lane & half) != 0;
    float sr = hi ? (or_ - xr) : (xr + or_);
    float si = hi ? (oi_ - xi) : (xi + oi_);
    int e = (lane & (half-1)) << k;
    float wr2 = hi ? twr[e] : 1.f;
    float wi2 = hi ? sgn*twi[e] : 0.f;
    xr = sr*wr2 - si*wi2;
    xi = sr*wi2 + si*wr2;
  }
  int rev = __brev((unsigned)lane) >> 26;
  xr = __shfl(xr, rev, 64);
  xi = __shfl(xi, rev, 64);
}

// ---------------- init: zero + pack posq + pack nbr/shifts ------------------
__global__ __launch_bounds__(256) void init_kernel(
    const float* __restrict__ pos, const float* __restrict__ q,
    const int* __restrict__ nbr, const int* __restrict__ shifts,
    float* __restrict__ zbase, float4* __restrict__ posq, int* __restrict__ nbs){
  int t = blockIdx.x*256 + threadIdx.x;
  if(t < ZERO_LEN) zbase[t] = 0.f;
  if(t < NATOM)
    posq[t] = make_float4(pos[3*t], pos[3*t+1], pos[3*t+2], q[t]);
  if(t < NPAIR){
    int j = nbr[t];
    int sx=shifts[3*t], sy=shifts[3*t+1], sz=shifts[3*t+2];
    int v;
    if(j < 0) v = -1;
    else v = (j & 0x7FFF) | ((sx+8)&15)<<15 | ((sy+8)&15)<<19 | ((sz+8)&15)<<23;
    nbs[t] = v;
  }
}

// ------- real-space pair sum: 4 atoms/wave, all loads hoisted up front ------
__global__ __launch_bounds__(256) void real_kernel(
    const float4* __restrict__ posq, const int* __restrict__ nbs,
    const float* __restrict__ cell,
    float* __restrict__ fi, float* __restrict__ gj, float* __restrict__ part){
  int lane = threadIdx.x & 63;
  int wid  = blockIdx.x*4 + (threadIdx.x>>6);
  int i0   = wid*4;
  float c0=cell[0],c1=cell[1],c2=cell[2];
  float c3=cell[3],c4=cell[4],c5=cell[5];
  float c6=cell[6],c7=cell[7],c8=cell[8];
  // ---- issue ALL loads first: 4 nbs words, 4 i-records, 4 j-gathers ----
  int v[4]; int jj[4]; float4 pi[4], pj[4];
#pragma unroll
  for(int k=0;k<4;k++) v[k]  = nbs[(i0+k)*NNBR + lane];
#pragma unroll
  for(int k=0;k<4;k++) pi[k] = posq[i0+k];
#pragma unroll
  for(int k=0;k<4;k++) jj[k] = min(v[k] & 0x7FFF, NATOM-1);
#pragma unroll
  for(int k=0;k<4;k++) pj[k] = posq[jj[k]];   // 4 independent gathers in flight
  float e=0.f, vxx=0.f,vyy=0.f,vzz=0.f,vxy=0.f,vxz=0.f,vyz=0.f;
#pragma unroll
  for(int k=0;k<4;k++){
    int i = i0 + k;
    int vv = v[k], j = jj[k];
    int sx=((vv>>15)&15)-8, sy=((vv>>19)&15)-8, sz=((vv>>23)&15)-8;
    bool valid = (vv>=0) && !((j==i) && (sx==0) && (sy==0) && (sz==0));
    float rx = pj[k].x - pi[k].x + sx*c0 + sy*c3 + sz*c6;
    float ry = pj[k].y - pi[k].y + sx*c1 + sy*c4 + sz*c7;
    float rz = pj[k].z - pi[k].z + sx*c2 + sy*c5 + sz*c8;
    float r2 = rx*rx + ry*ry + rz*rz;
    float s = 0.f;
    if(valid && r2 > 0.f && r2 < RC2){
      float r = sqrtf(r2);
      float ar = ALPHA_C * r;
      float qq = pi[k].w * pj[k].w;
      float ef = erfcf(ar);
      float ex = expf(-ar*ar);
      float ir = 1.f/r;
      e += 0.5f*qq*ef*ir;
      s  = 0.5f*qq*(ef + TWO_OVER_SQRTPI*ar*ex)*ir*ir*ir;
    }
    float gx = s*rx, gy = s*ry, gz = s*rz;
    if(s != 0.f){
      unsafeAtomicAdd(&gj[3*j+0], -gx);
      unsafeAtomicAdd(&gj[3*j+1], -gy);
      unsafeAtomicAdd(&gj[3*j+2], -gz);
    }
    vxx -= s*rx*rx; vyy -= s*ry*ry; vzz -= s*rz*rz;
    vxy -= s*rx*ry; vxz -= s*rx*rz; vyz -= s*ry*rz;
    float tgx = wsum64(gx), tgy = wsum64(gy), tgz = wsum64(gz);
    if(lane==0){ fi[3*i]=tgx; fi[3*i+1]=tgy; fi[3*i+2]=tgz; }
  }
  e   = wsum64(e);
  vxx = wsum64(vxx); vyy = wsum64(vyy); vzz = wsum64(vzz);
  vxy = wsum64(vxy); vxz = wsum64(vxz); vyz = wsum64(vyz);
  if(lane==0){
    float* slot = part + (wid & 63)*16;
    unsafeAtomicAdd(&slot[0], e);
    unsafeAtomicAdd(&slot[1], vxx); unsafeAtomicAdd(&slot[2], vyy); unsafeAtomicAdd(&slot[3], vzz);
    unsafeAtomicAdd(&slot[4], vxy); unsafeAtomicAdd(&slot[5], vxz); unsafeAtomicAdd(&slot[6], vyz);
  }
}

// ---------------- B-spline spreading: one wave/atom, one lane/point ---------
__global__ __launch_bounds__(256) void spread_kernel(
    const float4* __restrict__ posq, const float* __restrict__ cell,
    float* __restrict__ mesh){
  int wid  = blockIdx.x*4 + (threadIdx.x>>6);
  int lane = threadIdx.x & 63;
  float h[9]; hinv9(cell, h);
  float4 pq = posq[wid];
  float u0=(pq.x*h[0]+pq.y*h[3]+pq.z*h[6])*(float)KM;
  float u1=(pq.x*h[1]+pq.y*h[4]+pq.z*h[7])*(float)KM;
  float u2=(pq.x*h[2]+pq.y*h[5]+pq.z*h[8])*(float)KM;
  float b0=floorf(u0), b1=floorf(u1), b2=floorf(u2);
  float t0=u0-b0, t1=u1-b1, t2=u2-b2;
  int i0=(int)b0, i1=(int)b1, i2=(int)b2;
  int a = lane>>4, b = (lane>>2)&3, c = lane&3;
  float w = pq.w * M4f(t0+(float)a) * M4f(t1+(float)b) * M4f(t2+(float)c);
  int ix=(i0-a+256)&63, iy=(i1-b+256)&63, iz=(i2-c+256)&63;
  unsafeAtomicAdd(&mesh[(ix*KM + iy)*KM + iz], w);
}

// ---------------- fftZ forward: 4 contiguous z-lines per block --------------
__global__ __launch_bounds__(256) void fftZF(const float* __restrict__ mesh,
                                             float* __restrict__ re, float* __restrict__ im){
  __shared__ float twr[64], twi[64];
  int t = threadIdx.x, lane = t&63;
  fill_tw(t, twr, twi);
  __syncthreads();
  int idx = blockIdx.x*256 + t;
  float xr = mesh[idx], xi = 0.f;
  fft64t(xr, xi, lane, twr, twi, 1.f);
  re[idx]=xr; im[idx]=xi;
}

// ---------------- fftZ inverse: write real part only (phi) ------------------
__global__ __launch_bounds__(256) void fftZI(float* __restrict__ re, const float* __restrict__ im){
  __shared__ float twr[64], twi[64];
  int t = threadIdx.x, lane = t&63;
  fill_tw(t, twr, twi);
  __syncthreads();
  int idx = blockIdx.x*256 + t;
  float xr = re[idx], xi = im[idx];
  fft64t(xr, xi, lane, twr, twi, -1.f);
  re[idx]=xr;
}

// ---------------- fftY: 64y x 16z tile per block, dir = +-1 -----------------
__global__ __launch_bounds__(256) void fftY(float* __restrict__ re, float* __restrict__ im,
                                            float sgn){
  __shared__ float lr[64][17], li[64][17], twr[64], twi[64];
  int t = threadIdx.x, lane = t&63, w = t>>6;
  fill_tw(t, twr, twi);
  int x = blockIdx.x>>2, z0 = (blockIdx.x&3)*16;
  int off = x*4096 + z0;
#pragma unroll
  for(int k=0;k<4;k++){
    int e = k*256 + t; int y = e>>4, zz = e&15;
    lr[y][zz] = re[off + y*64 + zz];
    li[y][zz] = im[off + y*64 + zz];
  }
  __syncthreads();
#pragma unroll
  for(int qq=0; qq<4; qq++){
    int zz = w*4 + qq;
    float xr = lr[lane][zz], xi = li[lane][zz];
    fft64t(xr, xi, lane, twr, twi, sgn);
    lr[lane][zz] = xr; li[lane][zz] = xi;
  }
  __syncthreads();
#pragma unroll
  for(int k=0;k<4;k++){
    int e = k*256 + t; int y = e>>4, zz = e&15;
    re[off + y*64 + zz] = lr[y][zz];
    im[off + y*64 + zz] = li[y][zz];
  }
}

// ------- fftBC: forward x + kmul + inverse x, all in-register per tile ------
__global__ __launch_bounds__(256) void fftBC(float* __restrict__ re, float* __restrict__ im,
                                             const float* __restrict__ cell,
                                             float* __restrict__ part){
  __shared__ float lr[64][17], li[64][17], cf[64], twr[64], twi[64];
  int t = threadIdx.x, lane = t&63, w = t>>6;
  int y = blockIdx.x>>2, z0 = (blockIdx.x&3)*16;
  float h[9]; hinv9(cell, h);
  fill_tw(t, twr, twi);
  if(t < 64){
    float p1 = TWOPI_F*(float)t/64.f;
    float s1,c1_,s2,c2_; sincosf(p1,&s1,&c1_); sincosf(2.f*p1,&s2,&c2_);
    float dre = (1.f/6.f) + (2.f/3.f)*c1_ + (1.f/6.f)*c2_;
    float dim = (2.f/3.f)*s1 + (1.f/6.f)*s2;
    cf[t] = 1.f/(dre*dre + dim*dim);
  }
  float* rp = re + y*64 + z0;
  float* ip = im + y*64 + z0;
#pragma unroll
  for(int k=0;k<4;k++){
    int e = k*256 + t; int xI = e>>4, zz = e&15;
    lr[xI][zz] = rp[xI*4096 + zz];
    li[xI][zz] = ip[xI*4096 + zz];
  }
  __syncthreads();
  const float inv4a2 = 1.f/(4.f*ALPHA_C*ALPHA_C);
  float my_f = (float)((y<32)? y : y-64);
  float sE=0.f, v0=0.f,v1=0.f,v2=0.f,v3=0.f,v4=0.f,v5=0.f;
#pragma unroll
  for(int qq=0; qq<4; qq++){
    int zz = w*4 + qq; int z = z0 + zz;
    float xr = lr[lane][zz], xi = li[lane][zz];
    fft64t(xr, xi, lane, twr, twi, 1.f);   // lane = mx
    int mx = lane, mz = z;
    float fx = (float)((mx<32)? mx : mx-64);
    float fz = (float)((mz<32)? mz : mz-64);
    float kx = TWOPI_F*(fx*h[0] + my_f*h[1] + fz*h[2]);
    float ky = TWOPI_F*(fx*h[3] + my_f*h[4] + fz*h[5]);
    float kz = TWOPI_F*(fx*h[6] + my_f*h[7] + fz*h[8]);
    float k2 = kx*kx + ky*ky + kz*kz;
    float wk = 0.f;
    if(k2 > 0.f){
      float kern = expf(-k2*inv4a2)/k2;
      wk = kern * cf[mx]*cf[y]*cf[z];
      float q2 = xr*xr + xi*xi;
      sE += wk*q2;
      float fac = wk*q2*(inv4a2 + 1.f/k2)*2.f;
      v0 += fac*kx*kx; v1 += fac*ky*ky; v2 += fac*kz*kz;
      v3 += fac*kx*ky; v4 += fac*kx*kz; v5 += fac*ky*kz;
    }
    xr *= wk; xi *= wk;
    fft64t(xr, xi, lane, twr, twi, -1.f);  // inverse x immediately, in-register
    lr[lane][zz] = xr; li[lane][zz] = xi;
  }
  __syncthreads();
#pragma unroll
  for(int k=0;k<4;k++){
    int e = k*256 + t; int xI = e>>4, zz = e&15;
    rp[xI*4096 + zz] = lr[xI][zz];
    ip[xI*4096 + zz] = li[xI][zz];
  }
  sE = wsum64(sE);
  v0 = wsum64(v0); v1 = wsum64(v1); v2 = wsum64(v2);
  v3 = wsum64(v3); v4 = wsum64(v4); v5 = wsum64(v5);
  if(lane==0){
    float* slot = part + (((blockIdx.x<<2)|w)&63)*16;
    unsafeAtomicAdd(&slot[7],  sE);
    unsafeAtomicAdd(&slot[8],  v0); unsafeAtomicAdd(&slot[9],  v1);
    unsafeAtomicAdd(&slot[10], v2); unsafeAtomicAdd(&slot[11], v3);
    unsafeAtomicAdd(&slot[12], v4); unsafeAtomicAdd(&slot[13], v5);
  }
}

// ---------------- gather + merged finalize ----------------------------------
__global__ __launch_bounds__(256) void gather_kernel(
    const float4* __restrict__ posq, const float* __restrict__ cell,
    const float* __restrict__ phi,
    const float* __restrict__ fi, const float* __restrict__ gj,
    const float* __restrict__ part, float* __restrict__ out){
  __shared__ float sa[256], sb[256], facc[16];
  int wid  = blockIdx.x*4 + (threadIdx.x>>6);
  int lane = threadIdx.x & 63;
  float h[9]; float V = hinv9(cell, h);
  float4 pq = posq[wid];
  float u0=(pq.x*h[0]+pq.y*h[3]+pq.z*h[6])*(float)KM;
  float u1=(pq.x*h[1]+pq.y*h[4]+pq.z*h[7])*(float)KM;
  float u2=(pq.x*h[2]+pq.y*h[5]+pq.z*h[8])*(float)KM;
  float b0=floorf(u0), b1=floorf(u1), b2=floorf(u2);
  float t0=u0-b0, t1=u1-b1, t2=u2-b2;
  int i0=(int)b0, i1=(int)b1, i2=(int)b2;
  int a = lane>>4, b = (lane>>2)&3, c = lane&3;
  float fa=(float)a, fb=(float)b, fc=(float)c;
  float wxa=M4f(t0+fa), wyb=M4f(t1+fb), wzc=M4f(t2+fc);
  float dxa=M3f(t0+fa)-M3f(t0+fa-1.f);
  float dyb=M3f(t1+fb)-M3f(t1+fb-1.f);
  float dzc=M3f(t2+fc)-M3f(t2+fc-1.f);
  int ix=(i0-a+256)&63, iy=(i1-b+256)&63, iz=(i2-c+256)&63;
  float p = phi[(ix*KM + iy)*KM + iz];
  float Sx = wsum64(p*dxa*wyb*wzc);
  float Sy = wsum64(p*wxa*dyb*wzc);
  float Sz = wsum64(p*wxa*wyb*dzc);
  if(lane==0){
    float scale = pq.w * (2.f*TWOPI_F/V) * (float)KM;
    float g0 = scale*(Sx*h[0] + Sy*h[1] + Sz*h[2]);
    float g1 = scale*(Sx*h[3] + Sy*h[4] + Sz*h[5]);
    float g2 = scale*(Sx*h[6] + Sy*h[7] + Sz*h[8]);
    out[1+3*wid+0] = -KE_C*(fi[3*wid+0] + gj[3*wid+0] + g0);
    out[1+3*wid+1] = -KE_C*(fi[3*wid+1] + gj[3*wid+1] + g1);
    out[1+3*wid+2] = -KE_C*(fi[3*wid+2] + gj[3*wid+2] + g2);
  }
  if(blockIdx.x==0){
    int t = threadIdx.x;
    float qa=0.f, qb=0.f;
    for(int i=t;i<NATOM;i+=256){ float qv=posq[i].w; qa+=qv; qb+=qv*qv; }
    sa[t]=qa; sb[t]=qb; __syncthreads();
    for(int off=128; off>0; off>>=1){
      if(t<off){ sa[t]+=sa[t+off]; sb[t]+=sb[t+off]; } __syncthreads();
    }
    if(t<14){ float s=0.f; for(int sl=0;sl<64;sl++) s+=part[sl*16+t]; facc[t]=s; }
    __syncthreads();
    if(t==0){
      float qtot = sa[0], sumq2 = sb[0];
      float a2 = ALPHA_C*ALPHA_C;
      float pref = TWOPI_F/V;
      float e_real = facc[0];
      float e_rec  = pref*facc[7];
      float e_self = -(ALPHA_C/sqrtf(PI_F))*sumq2;
      float e_bg   = -(PI_F/(2.f*a2*V))*qtot*qtot;
      out[0] = (e_real + e_rec + e_self + e_bg)*KE_C;
      float gxx = facc[1] + pref*facc[8]  - e_rec - e_bg;
      float gyy = facc[2] + pref*facc[9]  - e_rec - e_bg;
      float gzz = facc[3] + pref*facc[10] - e_rec - e_bg;
      float gxy = facc[4] + pref*facc[11];
      float gxz = facc[5] + pref*facc[12];
      float gyz = facc[6] + pref*facc[13];
      float cc = -KE_C/V;
      float* st = out + 1 + 3*NATOM;
      st[0]=cc*gxx; st[4]=cc*gyy; st[8]=cc*gzz;
      st[1]=cc*gxy; st[3]=cc*gxy;
      st[2]=cc*gxz; st[6]=cc*gxz;
      st[5]=cc*gyz; st[7]=cc*gyz;
    }
  }
}

extern "C" void kernel_launch(void* const* d_in, const int* in_sizes, int n_in,
                              void* d_out, int out_size, void* d_ws, size_t ws_size,
                              hipStream_t stream) {
  const float* pos  = (const float*)d_in[0];
  const float* q    = (const float*)d_in[1];
  const float* cell = (const float*)d_in[2];
  const int* nbr    = (const int*)d_in[3];
  const int* shifts = (const int*)d_in[4];
  float* out = (float*)d_out;
  float* ws  = (float*)d_ws;
  float*  bufRe = ws + WS_RE;
  float*  bufIm = ws + WS_IM;
  float*  mesh  = ws + WS_MESH;
  float*  gj    = ws + WS_GJ;
  float*  part  = ws + WS_PART;
  float*  fi    = ws + WS_FI;
  float4* posq  = (float4*)(ws + WS_POSQ);
  int*    nbs   = (int*)(ws + WS_NBS);

  init_kernel<<<(NPAIR+255)/256,256,0,stream>>>(pos, q, nbr, shifts, mesh, posq, nbs);
  real_kernel<<<1250,256,0,stream>>>(posq, nbs, cell, fi, gj, part);
  spread_kernel<<<5000,256,0,stream>>>(posq, cell, mesh);
  fftZF<<<1024,256,0,stream>>>(mesh, bufRe, bufIm);
  fftY <<< 256,256,0,stream>>>(bufRe, bufIm, 1.f);
  fftBC<<< 256,256,0,stream>>>(bufRe, bufIm, cell, part);
  fftY <<< 256,256,0,stream>>>(bufRe, bufIm, -1.f);
  fftZI<<<1024,256,0,stream>>>(bufRe, bufIm);
  gather_kernel<<<5000,256,0,stream>>>(posq, cell, bufRe, fi, gj, part, out);
}

// Round 10
// 179.820 us; speedup vs baseline: 1.9363x; 1.0319x over previous
//
#include <hip/hip_runtime.h>
#include <math.h>

#define NATOM 20000
#define NNBR  64
#define KM    64
#define KM3   (KM*KM*KM)
#define NPAIR (NATOM*NNBR)

#define ALPHA_C 0.35f
#define KE_C    14.399645478425668f
#define TWO_OVER_SQRTPI 1.1283791670955126f
#define TWOPI_F 6.2831853071795864f
#define PI_F    3.14159265358979f
#define RC2     661.2244898f   /* (9/alpha)^2 */

// workspace layout (float offsets)
#define WS_RE    0
#define WS_IM    (KM3)
#define WS_MESH  (2*KM3)                  // zeroed ----
#define WS_GJ    (3*KM3)                  // 3*NATOM, zeroed
#define WS_PART  (3*KM3 + 3*NATOM)        // 64 slots * 16 fields, zeroed ----
#define WS_FI    (WS_PART + 1024)         // 3*NATOM, plain-stored
#define WS_POSQ  (WS_FI + 3*NATOM)        // 4*NATOM (float4, 16B-aligned)
#define WS_NBS   (WS_POSQ + 4*NATOM)      // NPAIR packed ints
#define ZERO_LEN (KM3 + 3*NATOM + 1024)
// part fields: 0=e_real, 1..6=geps_real, 7=sE_rec, 8..13=sV

__device__ __forceinline__ float M2f(float x){ return fmaxf(0.f, 1.f - fabsf(x - 1.f)); }
__device__ __forceinline__ float M3f(float x){ return (x*M2f(x) + (3.f-x)*M2f(x-1.f)) * 0.5f; }
__device__ __forceinline__ float M4f(float x){ return (x*M3f(x) + (4.f-x)*M3f(x-1.f)) * (1.f/3.f); }

__device__ __forceinline__ float wsum64(float v){
#pragma unroll
  for(int off=32; off>0; off>>=1) v += __shfl_xor(v, off, 64);
  return v;
}

// 3x3 inverse of row-major cell; returns |det|
__device__ __forceinline__ float hinv9(const float* __restrict__ cell, float* h){
  float m00=cell[0],m01=cell[1],m02=cell[2];
  float m10=cell[3],m11=cell[4],m12=cell[5];
  float m20=cell[6],m21=cell[7],m22=cell[8];
  float det = m00*(m11*m22-m12*m21) - m01*(m10*m22-m12*m20) + m02*(m10*m21-m11*m20);
  float id = 1.f/det;
  h[0]=(m11*m22-m12*m21)*id; h[1]=(m02*m21-m01*m22)*id; h[2]=(m01*m12-m02*m11)*id;
  h[3]=(m12*m20-m10*m22)*id; h[4]=(m00*m22-m02*m20)*id; h[5]=(m02*m10-m00*m12)*id;
  h[6]=(m10*m21-m11*m20)*id; h[7]=(m01*m20-m00*m21)*id; h[8]=(m00*m11-m01*m10)*id;
  return fabsf(det);
}

// fill forward twiddle tables (twr=cos, twi=-sin) from threads t<64
__device__ __forceinline__ void fill_tw(int t, float* twr, float* twi){
  if(t < 64){
    float ss, cc; sincosf((TWOPI_F/64.f)*(float)t, &ss, &cc);
    twr[t] = cc; twi[t] = -ss;
  }
}

// in-register 64-point FFT across the wave; sgn=+1 forward, -1 inverse
__device__ __forceinline__ void fft64t(float& xr, float& xi, int lane,
                                       const float* __restrict__ twr,
                                       const float* __restrict__ twi, float sgn){
#pragma unroll
  for(int k=0;k<6;k++){
    int half = 32 >> k;
    float or_ = __shfl_xor(xr, half, 64);
    float oi_ = __shfl_xor(xi, half, 64);
    bool hi = (lane & half) != 0;
    float sr = hi ? (or_ - xr) : (xr + or_);
    float si = hi ? (oi_ - xi) : (xi + oi_);
    int e = (lane & (half-1)) << k;
    float wr2 = hi ? twr[e] : 1.f;
    float wi2 = hi ? sgn*twi[e] : 0.f;
    xr = sr*wr2 - si*wi2;
    xi = sr*wi2 + si*wr2;
  }
  int rev = __brev((unsigned)lane) >> 26;
  xr = __shfl(xr, rev, 64);
  xi = __shfl(xi, rev, 64);
}

// ---------------- init: zero + pack posq + pack nbr/shifts ------------------
__global__ __launch_bounds__(256) void init_kernel(
    const float* __restrict__ pos, const float* __restrict__ q,
    const int* __restrict__ nbr, const int* __restrict__ shifts,
    float* __restrict__ zbase, float4* __restrict__ posq, int* __restrict__ nbs){
  int t = blockIdx.x*256 + threadIdx.x;
  if(t < ZERO_LEN) zbase[t] = 0.f;
  if(t < NATOM)
    posq[t] = make_float4(pos[3*t], pos[3*t+1], pos[3*t+2], q[t]);
  if(t < NPAIR){
    int j = nbr[t];
    int sx=shifts[3*t], sy=shifts[3*t+1], sz=shifts[3*t+2];
    int v;
    if(j < 0) v = -1;
    else v = (j & 0x7FFF) | ((sx+8)&15)<<15 | ((sy+8)&15)<<19 | ((sz+8)&15)<<23;
    nbs[t] = v;
  }
}

// ------- realspread: blocks 0..1249 real pairs, 1250..6249 spread -----------
__global__ __launch_bounds__(256) void realspread_kernel(
    const float4* __restrict__ posq, const int* __restrict__ nbs,
    const float* __restrict__ cell,
    float* __restrict__ fi, float* __restrict__ gj, float* __restrict__ part,
    float* __restrict__ mesh){
  int lane = threadIdx.x & 63;
  if(blockIdx.x < 1250){
    // ---------------- real-space: 4 atoms/wave, loads hoisted ----------------
    int wid  = blockIdx.x*4 + (threadIdx.x>>6);
    int i0   = wid*4;
    float c0=cell[0],c1=cell[1],c2=cell[2];
    float c3=cell[3],c4=cell[4],c5=cell[5];
    float c6=cell[6],c7=cell[7],c8=cell[8];
    int v[4]; int jj[4]; float4 pi[4], pj[4];
#pragma unroll
    for(int k=0;k<4;k++) v[k]  = nbs[(i0+k)*NNBR + lane];
#pragma unroll
    for(int k=0;k<4;k++) pi[k] = posq[i0+k];
#pragma unroll
    for(int k=0;k<4;k++) jj[k] = min(v[k] & 0x7FFF, NATOM-1);
#pragma unroll
    for(int k=0;k<4;k++) pj[k] = posq[jj[k]];   // 4 independent gathers in flight
    float e=0.f, vxx=0.f,vyy=0.f,vzz=0.f,vxy=0.f,vxz=0.f,vyz=0.f;
#pragma unroll
    for(int k=0;k<4;k++){
      int i = i0 + k;
      int vv = v[k], j = jj[k];
      int sx=((vv>>15)&15)-8, sy=((vv>>19)&15)-8, sz=((vv>>23)&15)-8;
      bool valid = (vv>=0) && !((j==i) && (sx==0) && (sy==0) && (sz==0));
      float rx = pj[k].x - pi[k].x + sx*c0 + sy*c3 + sz*c6;
      float ry = pj[k].y - pi[k].y + sx*c1 + sy*c4 + sz*c7;
      float rz = pj[k].z - pi[k].z + sx*c2 + sy*c5 + sz*c8;
      float r2 = rx*rx + ry*ry + rz*rz;
      float s = 0.f;
      if(valid && r2 > 0.f && r2 < RC2){
        float r = sqrtf(r2);
        float ar = ALPHA_C * r;
        float qq = pi[k].w * pj[k].w;
        float ef = erfcf(ar);
        float ex = expf(-ar*ar);
        float ir = 1.f/r;
        e += 0.5f*qq*ef*ir;
        s  = 0.5f*qq*(ef + TWO_OVER_SQRTPI*ar*ex)*ir*ir*ir;
      }
      float gx = s*rx, gy = s*ry, gz = s*rz;
      if(s != 0.f){
        unsafeAtomicAdd(&gj[3*j+0], -gx);
        unsafeAtomicAdd(&gj[3*j+1], -gy);
        unsafeAtomicAdd(&gj[3*j+2], -gz);
      }
      vxx -= s*rx*rx; vyy -= s*ry*ry; vzz -= s*rz*rz;
      vxy -= s*rx*ry; vxz -= s*rx*rz; vyz -= s*ry*rz;
      float tgx = wsum64(gx), tgy = wsum64(gy), tgz = wsum64(gz);
      if(lane==0){ fi[3*i]=tgx; fi[3*i+1]=tgy; fi[3*i+2]=tgz; }
    }
    e   = wsum64(e);
    vxx = wsum64(vxx); vyy = wsum64(vyy); vzz = wsum64(vzz);
    vxy = wsum64(vxy); vxz = wsum64(vxz); vyz = wsum64(vyz);
    if(lane==0){
      float* slot = part + (wid & 63)*16;
      unsafeAtomicAdd(&slot[0], e);
      unsafeAtomicAdd(&slot[1], vxx); unsafeAtomicAdd(&slot[2], vyy); unsafeAtomicAdd(&slot[3], vzz);
      unsafeAtomicAdd(&slot[4], vxy); unsafeAtomicAdd(&slot[5], vxz); unsafeAtomicAdd(&slot[6], vyz);
    }
  } else {
    // ---------------- spread: one wave/atom, one lane/stencil point ---------
    int wid = (blockIdx.x - 1250)*4 + (threadIdx.x>>6);
    float h[9]; hinv9(cell, h);
    float4 pq = posq[wid];
    float u0=(pq.x*h[0]+pq.y*h[3]+pq.z*h[6])*(float)KM;
    float u1=(pq.x*h[1]+pq.y*h[4]+pq.z*h[7])*(float)KM;
    float u2=(pq.x*h[2]+pq.y*h[5]+pq.z*h[8])*(float)KM;
    float b0=floorf(u0), b1=floorf(u1), b2=floorf(u2);
    float t0=u0-b0, t1=u1-b1, t2=u2-b2;
    int i0=(int)b0, i1=(int)b1, i2=(int)b2;
    int a = lane>>4, b = (lane>>2)&3, c = lane&3;
    float w = pq.w * M4f(t0+(float)a) * M4f(t1+(float)b) * M4f(t2+(float)c);
    int ix=(i0-a+256)&63, iy=(i1-b+256)&63, iz=(i2-c+256)&63;
    unsafeAtomicAdd(&mesh[(ix*KM + iy)*KM + iz], w);
  }
}

// ---------------- fftZ forward: 4 contiguous z-lines per block --------------
__global__ __launch_bounds__(256) void fftZF(const float* __restrict__ mesh,
                                             float* __restrict__ re, float* __restrict__ im){
  __shared__ float twr[64], twi[64];
  int t = threadIdx.x, lane = t&63;
  fill_tw(t, twr, twi);
  __syncthreads();
  int idx = blockIdx.x*256 + t;
  float xr = mesh[idx], xi = 0.f;
  fft64t(xr, xi, lane, twr, twi, 1.f);
  re[idx]=xr; im[idx]=xi;
}

// ---------------- fftZ inverse: write real part only (phi) ------------------
__global__ __launch_bounds__(256) void fftZI(float* __restrict__ re, const float* __restrict__ im){
  __shared__ float twr[64], twi[64];
  int t = threadIdx.x, lane = t&63;
  fill_tw(t, twr, twi);
  __syncthreads();
  int idx = blockIdx.x*256 + t;
  float xr = re[idx], xi = im[idx];
  fft64t(xr, xi, lane, twr, twi, -1.f);
  re[idx]=xr;
}

// ---------------- fftY: 64y x 16z tile per block, dir = +-1 -----------------
__global__ __launch_bounds__(256) void fftY(float* __restrict__ re, float* __restrict__ im,
                                            float sgn){
  __shared__ float lr[64][17], li[64][17], twr[64], twi[64];
  int t = threadIdx.x, lane = t&63, w = t>>6;
  fill_tw(t, twr, twi);
  int x = blockIdx.x>>2, z0 = (blockIdx.x&3)*16;
  int off = x*4096 + z0;
#pragma unroll
  for(int k=0;k<4;k++){
    int e = k*256 + t; int y = e>>4, zz = e&15;
    lr[y][zz] = re[off + y*64 + zz];
    li[y][zz] = im[off + y*64 + zz];
  }
  __syncthreads();
#pragma unroll
  for(int qq=0; qq<4; qq++){
    int zz = w*4 + qq;
    float xr = lr[lane][zz], xi = li[lane][zz];
    fft64t(xr, xi, lane, twr, twi, sgn);
    lr[lane][zz] = xr; li[lane][zz] = xi;
  }
  __syncthreads();
#pragma unroll
  for(int k=0;k<4;k++){
    int e = k*256 + t; int y = e>>4, zz = e&15;
    re[off + y*64 + zz] = lr[y][zz];
    im[off + y*64 + zz] = li[y][zz];
  }
}

// ------- fftBC: forward x + kmul + inverse x, all in-register per tile ------
__global__ __launch_bounds__(256) void fftBC(float* __restrict__ re, float* __restrict__ im,
                                             const float* __restrict__ cell,
                                             float* __restrict__ part){
  __shared__ float lr[64][17], li[64][17], cf[64], twr[64], twi[64];
  int t = threadIdx.x, lane = t&63, w = t>>6;
  int y = blockIdx.x>>2, z0 = (blockIdx.x&3)*16;
  float h[9]; hinv9(cell, h);
  fill_tw(t, twr, twi);
  if(t < 64){
    float p1 = TWOPI_F*(float)t/64.f;
    float s1,c1_,s2,c2_; sincosf(p1,&s1,&c1_); sincosf(2.f*p1,&s2,&c2_);
    float dre = (1.f/6.f) + (2.f/3.f)*c1_ + (1.f/6.f)*c2_;
    float dim = (2.f/3.f)*s1 + (1.f/6.f)*s2;
    cf[t] = 1.f/(dre*dre + dim*dim);
  }
  float* rp = re + y*64 + z0;
  float* ip = im + y*64 + z0;
#pragma unroll
  for(int k=0;k<4;k++){
    int e = k*256 + t; int xI = e>>4, zz = e&15;
    lr[xI][zz] = rp[xI*4096 + zz];
    li[xI][zz] = ip[xI*4096 + zz];
  }
  __syncthreads();
  const float inv4a2 = 1.f/(4.f*ALPHA_C*ALPHA_C);
  float my_f = (float)((y<32)? y : y-64);
  float sE=0.f, v0=0.f,v1=0.f,v2=0.f,v3=0.f,v4=0.f,v5=0.f;
#pragma unroll
  for(int qq=0; qq<4; qq++){
    int zz = w*4 + qq; int z = z0 + zz;
    float xr = lr[lane][zz], xi = li[lane][zz];
    fft64t(xr, xi, lane, twr, twi, 1.f);   // lane = mx
    int mx = lane, mz = z;
    float fx = (float)((mx<32)? mx : mx-64);
    float fz = (float)((mz<32)? mz : mz-64);
    float kx = TWOPI_F*(fx*h[0] + my_f*h[1] + fz*h[2]);
    float ky = TWOPI_F*(fx*h[3] + my_f*h[4] + fz*h[5]);
    float kz = TWOPI_F*(fx*h[6] + my_f*h[7] + fz*h[8]);
    float k2 = kx*kx + ky*ky + kz*kz;
    float wk = 0.f;
    if(k2 > 0.f){
      float kern = expf(-k2*inv4a2)/k2;
      wk = kern * cf[mx]*cf[y]*cf[z];
      float q2 = xr*xr + xi*xi;
      sE += wk*q2;
      float fac = wk*q2*(inv4a2 + 1.f/k2)*2.f;
      v0 += fac*kx*kx; v1 += fac*ky*ky; v2 += fac*kz*kz;
      v3 += fac*kx*ky; v4 += fac*kx*kz; v5 += fac*ky*kz;
    }
    xr *= wk; xi *= wk;
    fft64t(xr, xi, lane, twr, twi, -1.f);  // inverse x immediately, in-register
    lr[lane][zz] = xr; li[lane][zz] = xi;
  }
  __syncthreads();
#pragma unroll
  for(int k=0;k<4;k++){
    int e = k*256 + t; int xI = e>>4, zz = e&15;
    rp[xI*4096 + zz] = lr[xI][zz];
    ip[xI*4096 + zz] = li[xI][zz];
  }
  sE = wsum64(sE);
  v0 = wsum64(v0); v1 = wsum64(v1); v2 = wsum64(v2);
  v3 = wsum64(v3); v4 = wsum64(v4); v5 = wsum64(v5);
  if(lane==0){
    float* slot = part + (((blockIdx.x<<2)|w)&63)*16;
    unsafeAtomicAdd(&slot[7],  sE);
    unsafeAtomicAdd(&slot[8],  v0); unsafeAtomicAdd(&slot[9],  v1);
    unsafeAtomicAdd(&slot[10], v2); unsafeAtomicAdd(&slot[11], v3);
    unsafeAtomicAdd(&slot[12], v4); unsafeAtomicAdd(&slot[13], v5);
  }
}

// -------- gather: 4 atoms/wave, loads hoisted + merged finalize -------------
__global__ __launch_bounds__(256) void gather_kernel(
    const float4* __restrict__ posq, const float* __restrict__ cell,
    const float* __restrict__ phi,
    const float* __restrict__ fi, const float* __restrict__ gj,
    const float* __restrict__ part, float* __restrict__ out){
  __shared__ float sa[256], sb[256], facc[16];
  int lane = threadIdx.x & 63;
  int wid  = blockIdx.x*4 + (threadIdx.x>>6);
  int i0   = wid*4;
  float h[9]; float V = hinv9(cell, h);
  int a = lane>>4, b = (lane>>2)&3, c = lane&3;
  float fa=(float)a, fb=(float)b, fc=(float)c;
  // hoist: 4 posq loads, then 4 address computes, then 4 phi gathers in flight
  float4 pq[4];
#pragma unroll
  for(int k=0;k<4;k++) pq[k] = posq[i0+k];
  float t0[4], t1[4], t2[4]; float p[4];
#pragma unroll
  for(int k=0;k<4;k++){
    float u0=(pq[k].x*h[0]+pq[k].y*h[3]+pq[k].z*h[6])*(float)KM;
    float u1=(pq[k].x*h[1]+pq[k].y*h[4]+pq[k].z*h[7])*(float)KM;
    float u2=(pq[k].x*h[2]+pq[k].y*h[5]+pq[k].z*h[8])*(float)KM;
    float b0=floorf(u0), b1=floorf(u1), b2=floorf(u2);
    t0[k]=u0-b0; t1[k]=u1-b1; t2[k]=u2-b2;
    int ix=((int)b0-a+256)&63, iy=((int)b1-b+256)&63, iz=((int)b2-c+256)&63;
    p[k] = phi[(ix*KM + iy)*KM + iz];
  }
#pragma unroll
  for(int k=0;k<4;k++){
    float wxa=M4f(t0[k]+fa), wyb=M4f(t1[k]+fb), wzc=M4f(t2[k]+fc);
    float dxa=M3f(t0[k]+fa)-M3f(t0[k]+fa-1.f);
    float dyb=M3f(t1[k]+fb)-M3f(t1[k]+fb-1.f);
    float dzc=M3f(t2[k]+fc)-M3f(t2[k]+fc-1.f);
    float Sx = wsum64(p[k]*dxa*wyb*wzc);
    float Sy = wsum64(p[k]*wxa*dyb*wzc);
    float Sz = wsum64(p[k]*wxa*wyb*dzc);
    if(lane==0){
      int i = i0 + k;
      float scale = pq[k].w * (2.f*TWOPI_F/V) * (float)KM;
      float g0 = scale*(Sx*h[0] + Sy*h[1] + Sz*h[2]);
      float g1 = scale*(Sx*h[3] + Sy*h[4] + Sz*h[5]);
      float g2 = scale*(Sx*h[6] + Sy*h[7] + Sz*h[8]);
      out[1+3*i+0] = -KE_C*(fi[3*i+0] + gj[3*i+0] + g0);
      out[1+3*i+1] = -KE_C*(fi[3*i+1] + gj[3*i+1] + g1);
      out[1+3*i+2] = -KE_C*(fi[3*i+2] + gj[3*i+2] + g2);
    }
  }
  if(blockIdx.x==0){
    int t = threadIdx.x;
    float qa=0.f, qb=0.f;
    for(int i=t;i<NATOM;i+=256){ float qv=posq[i].w; qa+=qv; qb+=qv*qv; }
    sa[t]=qa; sb[t]=qb; __syncthreads();
    for(int off=128; off>0; off>>=1){
      if(t<off){ sa[t]+=sa[t+off]; sb[t]+=sb[t+off]; } __syncthreads();
    }
    if(t<14){ float s=0.f; for(int sl=0;sl<64;sl++) s+=part[sl*16+t]; facc[t]=s; }
    __syncthreads();
    if(t==0){
      float qtot = sa[0], sumq2 = sb[0];
      float a2 = ALPHA_C*ALPHA_C;
      float pref = TWOPI_F/V;
      float e_real = facc[0];
      float e_rec  = pref*facc[7];
      float e_self = -(ALPHA_C/sqrtf(PI_F))*sumq2;
      float e_bg   = -(PI_F/(2.f*a2*V))*qtot*qtot;
      out[0] = (e_real + e_rec + e_self + e_bg)*KE_C;
      float gxx = facc[1] + pref*facc[8]  - e_rec - e_bg;
      float gyy = facc[2] + pref*facc[9]  - e_rec - e_bg;
      float gzz = facc[3] + pref*facc[10] - e_rec - e_bg;
      float gxy = facc[4] + pref*facc[11];
      float gxz = facc[5] + pref*facc[12];
      float gyz = facc[6] + pref*facc[13];
      float cc = -KE_C/V;
      float* st = out + 1 + 3*NATOM;
      st[0]=cc*gxx; st[4]=cc*gyy; st[8]=cc*gzz;
      st[1]=cc*gxy; st[3]=cc*gxy;
      st[2]=cc*gxz; st[6]=cc*gxz;
      st[5]=cc*gyz; st[7]=cc*gyz;
    }
  }
}

extern "C" void kernel_launch(void* const* d_in, const int* in_sizes, int n_in,
                              void* d_out, int out_size, void* d_ws, size_t ws_size,
                              hipStream_t stream) {
  const float* pos  = (const float*)d_in[0];
  const float* q    = (const float*)d_in[1];
  const float* cell = (const float*)d_in[2];
  const int* nbr    = (const int*)d_in[3];
  const int* shifts = (const int*)d_in[4];
  float* out = (float*)d_out;
  float* ws  = (float*)d_ws;
  float*  bufRe = ws + WS_RE;
  float*  bufIm = ws + WS_IM;
  float*  mesh  = ws + WS_MESH;
  float*  gj    = ws + WS_GJ;
  float*  part  = ws + WS_PART;
  float*  fi    = ws + WS_FI;
  float4* posq  = (float4*)(ws + WS_POSQ);
  int*    nbs   = (int*)(ws + WS_NBS);

  init_kernel<<<(NPAIR+255)/256,256,0,stream>>>(pos, q, nbr, shifts, mesh, posq, nbs);
  realspread_kernel<<<6250,256,0,stream>>>(posq, nbs, cell, fi, gj, part, mesh);
  fftZF<<<1024,256,0,stream>>>(mesh, bufRe, bufIm);
  fftY <<< 256,256,0,stream>>>(bufRe, bufIm, 1.f);
  fftBC<<< 256,256,0,stream>>>(bufRe, bufIm, cell, part);
  fftY <<< 256,256,0,stream>>>(bufRe, bufIm, -1.f);
  fftZI<<<1024,256,0,stream>>>(bufRe, bufIm);
  gather_kernel<<<1250,256,0,stream>>>(posq, cell, bufRe, fi, gj, part, out);
}